// Round 11
// baseline (285.854 us; speedup 1.0000x reference)
//
#include <hip/hip_runtime.h>

#define NE 64
#define TAU 1e-4f  // 4-term split-bf16 score sigma ~5e-6 -> 20-sigma guard
#define LSTR 68    // 68 mod 32 = 4 -> 2-way (free) LDS access in epilogue

typedef __bf16 bf16x8 __attribute__((ext_vector_type(8)));
typedef float f32x4 __attribute__((ext_vector_type(4)));

// split f32 -> bf16 hi + bf16 lo (hi RNE, lo = RNE(x - hi); x-hi exact in f32)
__device__ __forceinline__ void split8(const float4 a0, const float4 a1,
                                       bf16x8& hi, bf16x8& lo) {
  const float xs[8] = {a0.x, a0.y, a0.z, a0.w, a1.x, a1.y, a1.z, a1.w};
#pragma unroll
  for (int i = 0; i < 8; ++i) {
    const __bf16 h = (__bf16)xs[i];
    hi[i] = h;
    lo[i] = (__bf16)(xs[i] - (float)h);
  }
}

// async global->LDS, 16B/lane; LDS dest = wave-uniform base + lane*16
__device__ __forceinline__ void gld16(const void* g, void* l) {
  __builtin_amdgcn_global_load_lds(
      (const __attribute__((address_space(1))) void*)g,
      (__attribute__((address_space(3))) void*)l, 16, 0, 0);
}

// ---- Kernel Z: zero cnt+hist ------------------------------------------------
__global__ void zero512(int* __restrict__ p) { p[threadIdx.x] = 0; }

// ---- Kernel 0: W -> bf16 hi/lo in FRAGMENT-MAJOR 32-k tiles (1 MB, once) ---
// elem(tt, j, lk, lr, kr) = tt*2048 + j*512 + (lk*16+lr)*8 + kr
// where W-row e = 16j+lr, k = 32tt + 8lk + kr.
__global__ __launch_bounds__(256) void wconvert(const float* __restrict__ W,
                                                __bf16* __restrict__ Whi,
                                                __bf16* __restrict__ Wlo,
                                                int n8, int H) {
  const int i = blockIdx.x * 256 + threadIdx.x;
  if (i >= n8) return;
  const int hc = H >> 3;
  const int e = i / hc;
  const int k0 = (i - e * hc) * 8;
  const float4 a0 = *reinterpret_cast<const float4*>(W + (size_t)e * H + k0);
  const float4 a1 =
      *reinterpret_cast<const float4*>(W + (size_t)e * H + k0 + 4);
  bf16x8 hi, lo;
  split8(a0, a1, hi, lo);
  const int tt = k0 >> 5, lk = (k0 >> 3) & 3, j = e >> 4, lr = e & 15;
  const size_t off = (size_t)tt * 2048 + j * 512 + (lk * 16 + lr) * 8;
  *reinterpret_cast<bf16x8*>(Whi + off) = hi;
  *reinterpret_cast<bf16x8*>(Wlo + off) = lo;
}

// ---- staging/compute helpers with COMPILE-TIME buffer index ----------------
// LDS map (bytes): A[buf] at buf*16384 (16 KB each), Bh[buf] at 32768+buf*8192,
// Bl[buf] at 49152+buf*8192. All offsets constant per template instantiation
// -> statically disjoint intervals -> SIInsertWaitcnts can keep the other
// buffer's global_load_lds DMAs in flight across this buffer's ds_reads.
template <int BUF>
__device__ __forceinline__ void issue_tile(int t, const float* const (&srcA)[4],
                                           const __bf16* srcBh,
                                           const __bf16* srcBl, char* smem,
                                           int wave) {
  float* af = (float*)(smem) + BUF * 4096;
  __bf16* bh = (__bf16*)(smem + 32768) + BUF * 4096;
  __bf16* bl = (__bf16*)(smem + 49152) + BUF * 4096;
#pragma unroll
  for (int p = 0; p < 4; ++p)
    gld16(srcA[p] + 64 * (size_t)t, af + wave * 1024 + p * 256);
  gld16(srcBh + 4096 * (size_t)t, bh + wave * 512);
  gld16(srcBh + 4096 * (size_t)t + 2048, bh + 2048 + wave * 512);
  gld16(srcBl + 4096 * (size_t)t, bl + wave * 512);
  gld16(srcBl + 4096 * (size_t)t + 2048, bl + 2048 + wave * 512);
}

template <int BUF>
__device__ __forceinline__ void compute_tile(char* smem, int wave, int lane,
                                             int lr, int lk, int swz,
                                             f32x4 (&acc)[4]) {
  const float* Aw = (float*)(smem) + BUF * 4096 + wave * 1024 + lr * 64;
  const __bf16* Bh0 = (__bf16*)(smem + 32768) + BUF * 4096;
  const __bf16* Bl0 = (__bf16*)(smem + 49152) + BUF * 4096;
#pragma unroll
  for (int kk = 0; kk < 2; ++kk) {
    const int c = 8 * kk + 2 * lk;  // even logical chunk
    const float4 f0 = *reinterpret_cast<const float4*>(Aw + 4 * (c ^ swz));
    const float4 f1 =
        *reinterpret_cast<const float4*>(Aw + 4 * ((c + 1) ^ swz));
    bf16x8 Ahi, Alo;
    split8(f0, f1, Ahi, Alo);
    const __bf16* Bh = Bh0 + kk * 2048;
    const __bf16* Bl = Bl0 + kk * 2048;
    bf16x8 BH[4], BL[4];
#pragma unroll
    for (int j = 0; j < 4; ++j) {
      BH[j] = *reinterpret_cast<const bf16x8*>(Bh + j * 512 + lane * 8);
      BL[j] = *reinterpret_cast<const bf16x8*>(Bl + j * 512 + lane * 8);
    }
    // term-major: 4 independent MFMAs back-to-back (ILP), per-acc order
    // identical to round 10 (lo*lo, lo*hi, hi*lo, hi*hi).
#pragma unroll
    for (int j = 0; j < 4; ++j)
      acc[j] = __builtin_amdgcn_mfma_f32_16x16x32_bf16(Alo, BL[j], acc[j], 0, 0, 0);
#pragma unroll
    for (int j = 0; j < 4; ++j)
      acc[j] = __builtin_amdgcn_mfma_f32_16x16x32_bf16(Alo, BH[j], acc[j], 0, 0, 0);
#pragma unroll
    for (int j = 0; j < 4; ++j)
      acc[j] = __builtin_amdgcn_mfma_f32_16x16x32_bf16(Ahi, BL[j], acc[j], 0, 0, 0);
#pragma unroll
    for (int j = 0; j < 4; ++j)
      acc[j] = __builtin_amdgcn_mfma_f32_16x16x32_bf16(Ahi, BH[j], acc[j], 0, 0, 0);
  }
}

// ------- Kernel 1: 4-term split-bf16 MFMA GEMM, BK=64, STATIC double-buffer -
__global__ __launch_bounds__(256, 2) void gemm_fused(
    const float* __restrict__ X, const __bf16* __restrict__ Whi,
    const __bf16* __restrict__ Wlo, const float* __restrict__ bias,
    float* __restrict__ S, float* __restrict__ wout, float* __restrict__ iout,
    int* __restrict__ cnt, int* __restrict__ hist, int* __restrict__ list,
    int cap, int H, int K) {
  __shared__ alignas(16) char smem[65536];
  __shared__ int hist_s[NE];
  const int tid = threadIdx.x;
  const int lane = tid & 63;
  const int wave = tid >> 6;
  if (tid < NE) hist_s[tid] = 0;
  const int lr = lane & 15;  // fragment row/col
  const int lk = lane >> 4;  // k sub-chunk
  const int row0 = blockIdx.x * 64;

  // A staging sources: instr p (0..3), lane -> row rr = 4p + (lane>>4),
  // phys slot sp = lane&15 holds logical chunk sp ^ (rr&7).
  const float* srcA[4];
#pragma unroll
  for (int p = 0; p < 4; ++p) {
    const int rr = 4 * p + (lane >> 4);
    const int sp = lane & 15;
    srcA[p] = X + (size_t)(row0 + 16 * wave + rr) * H + 4 * (sp ^ (rr & 7));
  }
  const __bf16* srcBh = Whi + wave * 512 + lane * 8;
  const __bf16* srcBl = Wlo + wave * 512 + lane * 8;

  f32x4 acc[4] = {};
  const int T2 = H / 64;  // 64 iterations (even)
  const int swz = lr & 7;

  issue_tile<0>(0, srcA, srcBh, srcBl, smem, wave);
  for (int t = 0; t < T2; t += 2) {
    // ---- tile t (buffer 0) ----
    if (t + 1 < T2) {
      issue_tile<1>(t + 1, srcA, srcBh, srcBl, smem, wave);
      asm volatile("s_waitcnt vmcnt(8)" ::: "memory");  // tile t landed
    } else {
      asm volatile("s_waitcnt vmcnt(0)" ::: "memory");
    }
    __builtin_amdgcn_s_barrier();
    asm volatile("" ::: "memory");
    compute_tile<0>(smem, wave, lane, lr, lk, swz, acc);
    asm volatile("" ::: "memory");
    __builtin_amdgcn_s_barrier();
    asm volatile("" ::: "memory");
    // ---- tile t+1 (buffer 1) ----
    if (t + 2 < T2) {
      issue_tile<0>(t + 2, srcA, srcBh, srcBl, smem, wave);
      asm volatile("s_waitcnt vmcnt(8)" ::: "memory");  // tile t+1 landed
    } else {
      asm volatile("s_waitcnt vmcnt(0)" ::: "memory");
    }
    __builtin_amdgcn_s_barrier();
    asm volatile("" ::: "memory");
    compute_tile<1>(smem, wave, lane, lr, lk, swz, acc);
    asm volatile("" ::: "memory");
    __builtin_amdgcn_s_barrier();
    asm volatile("" ::: "memory");
  }

  // ---- epilogue: transpose scores to token-major LDS (aliases smem) ----
  float* Ls = (float*)smem;  // 64*68*4 = 17408 B <= 65536
#pragma unroll
  for (int j = 0; j < 4; ++j)
#pragma unroll
    for (int r = 0; r < 4; ++r)
      Ls[(16 * wave + 4 * lk + r) * LSTR + 16 * j + lr] = acc[j][r];
  __syncthreads();

  const float bv = bias[lane];
  for (int tt = 0; tt < 16; ++tt) {
    const int tl = wave * 16 + tt;
    const int t = row0 + tl;
    const float s = Ls[tl * LSTR + lane] + bv;

    float m = s;
#pragma unroll
    for (int off = 32; off >= 1; off >>= 1) m = fmaxf(m, __shfl_xor(m, off));
    const float e = expf(s - m);
    float sum = e;
#pragma unroll
    for (int off = 32; off >= 1; off >>= 1) sum += __shfl_xor(sum, off);
    const float p = e / sum;

    // top-9 on biased raw score, lowest-index tie-break (matches lax.top_k)
    float wsel = s;
    float rv = 0.f;
    int ri = 0;
    float prev = 0.f, mingap = 1e30f;
#pragma unroll
    for (int r = 0; r < 9; ++r) {
      float v = wsel;
      int ii = lane;
#pragma unroll
      for (int off = 32; off >= 1; off >>= 1) {
        const float ov = __shfl_xor(v, off);
        const int oi = __shfl_xor(ii, off);
        if (ov > v || (ov == v && oi < ii)) { v = ov; ii = oi; }
      }
      if (r > 0) mingap = fminf(mingap, prev - v);
      prev = v;
      const float pw = __shfl(p, ii);
      if (lane == r) { rv = pw; ri = ii; }
      if (lane == ii) wsel = -1e30f;
    }

    bool toC = false;
    if (mingap < TAU && cap > 0) {
      int pos = 0;
      if (lane == 0) pos = atomicAdd(cnt, 1);
      pos = __shfl(pos, 0);
      if (pos < cap) {
        if (lane == 0) list[pos] = t;
        toC = true;  // recompute kernel produces all outputs for this token
      }
    }
    if (!toC) {
      S[(size_t)t * NE + lane] = p;
      if (lane < K) {
        wout[(size_t)t * K + lane] = rv;
        iout[(size_t)t * K + lane] = (float)ri;
        atomicAdd(&hist_s[ri], 1);
      }
    }
  }
  __syncthreads();
  if (tid < NE) atomicAdd(&hist[tid], hist_s[tid]);
}

// -------- f64 finalize for one token (lanes 0..63) ---------------
__device__ __forceinline__ void finalize_token_f64(
    int t, int lane, double s, float* __restrict__ S, float* __restrict__ wout,
    float* __restrict__ iout, int* __restrict__ hist, int K) {
  double m = s;
#pragma unroll
  for (int off = 32; off >= 1; off >>= 1) m = fmax(m, __shfl_xor(m, off));
  const double ex = exp(s - m);
  double sum = ex;
#pragma unroll
  for (int off = 32; off >= 1; off >>= 1) sum += __shfl_xor(sum, off);
  const double p = ex / sum;
  S[(size_t)t * NE + lane] = (float)p;
  double wsel = s;
  double rv = 0.0;
  int ri = 0;
  for (int r = 0; r < K; ++r) {
    double v = wsel;
    int ii = lane;
#pragma unroll
    for (int off = 32; off >= 1; off >>= 1) {
      const double ov = __shfl_xor(v, off);
      const int oi = __shfl_xor(ii, off);
      if (ov > v || (ov == v && oi < ii)) { v = ov; ii = oi; }
    }
    const double pw = __shfl(p, ii);
    if (lane == r) { rv = pw; ri = ii; }
    if (lane == ii) wsel = -1e300;
  }
  if (lane < K) {
    wout[(size_t)t * K + lane] = (float)rv;
    iout[(size_t)t * K + lane] = (float)ri;
    atomicAdd(&hist[ri], 1);
  }
}

// ------- Kernel 2: f64 recompute, 1 token/block, grid 512 -------------------
__global__ __launch_bounds__(256) void recompute_f64(
    const float* __restrict__ X, const float* __restrict__ W,
    const float* __restrict__ bias, float* __restrict__ S,
    float* __restrict__ wout, float* __restrict__ iout,
    const int* __restrict__ cnt, const int* __restrict__ list,
    int* __restrict__ hist, int H, int K, int cap) {
  if (cap <= 0) return;
  __shared__ float4 xs[1024];  // one token row (16 KB)
  __shared__ double red[256];
  const int tid = threadIdx.x;
  const int n = min(*cnt, cap);
  const int H4 = H >> 2;
  for (int idx = blockIdx.x; idx < n; idx += gridDim.x) {
    const int t = list[idx];
    __syncthreads();  // xs reuse from previous iteration
    const float4* xg = reinterpret_cast<const float4*>(X + (size_t)t * H);
    for (int i = tid; i < H4; i += 256) xs[i] = xg[i];
    __syncthreads();
    const int e = tid & 63, sl = tid >> 6;
    const int seg = H4 >> 2;  // 256 float4 per slice
    const float4* wr =
        reinterpret_cast<const float4*>(W + (size_t)e * H) + (size_t)sl * seg;
    const float4* xr = &xs[sl * seg];
    double a0 = 0.0, a1 = 0.0;  // split accumulators (break f64 dep chain)
    for (int k = 0; k < seg; k += 2) {
      const float4 w0 = wr[k], w1 = wr[k + 1];
      const float4 v0 = xr[k], v1 = xr[k + 1];
      a0 = fma((double)v0.x, (double)w0.x, a0);
      a0 = fma((double)v0.y, (double)w0.y, a0);
      a0 = fma((double)v0.z, (double)w0.z, a0);
      a0 = fma((double)v0.w, (double)w0.w, a0);
      a1 = fma((double)v1.x, (double)w1.x, a1);
      a1 = fma((double)v1.y, (double)w1.y, a1);
      a1 = fma((double)v1.z, (double)w1.z, a1);
      a1 = fma((double)v1.w, (double)w1.w, a1);
    }
    red[tid] = a0 + a1;
    __syncthreads();
    if (tid < 64) {
      const double s =
          red[e] + red[64 + e] + red[128 + e] + red[192 + e] + (double)bias[e];
      finalize_token_f64(t, e, s, S, wout, iout, hist, K);
    }
  }
}

// ------------- Kernel 3: bias update from integer histogram -----------------
__global__ void bias_update(const int* __restrict__ hist,
                            const float* __restrict__ bias,
                            float* __restrict__ bout, float tpe) {
  const int e = threadIdx.x;
  const float d = (float)hist[e] - tpe;
  const float sg = (d > 0.f) ? 1.f : ((d < 0.f) ? -1.f : 0.f);
  bout[e] = bias[e] + 0.01f * sg;
}

extern "C" void kernel_launch(void* const* d_in, const int* in_sizes, int n_in,
                              void* d_out, int out_size, void* d_ws, size_t ws_size,
                              hipStream_t stream) {
  const float* x = (const float*)d_in[0];
  const float* w = (const float*)d_in[1];
  const float* bias = (const float*)d_in[2];
  const int E = in_sizes[2];                       // 64
  const int H = in_sizes[1] / E;                   // 4096
  const long long N = (long long)in_sizes[0] / H;  // 32768 tokens
  const int K = (int)(((long long)out_size - N * E - E) / (2 * N));  // 8

  float* S = (float*)d_out;            // [N][E] probs
  float* wout = S + (size_t)N * E;     // [N][K]
  float* iout = wout + (size_t)N * K;  // [N][K] indices as float
  float* bout = iout + (size_t)N * K;  // [E]

  // ws: [0,4) cnt | [256,512) hist | Whi_f @4KB (512KB) | Wlo_f | list after
  int* cnt = (int*)d_ws;
  int* hist = (int*)d_ws + 64;
  const size_t whalf = (size_t)E * H * sizeof(__bf16);  // 512 KB
  __bf16* Whi = (__bf16*)((char*)d_ws + 4096);
  __bf16* Wlo = (__bf16*)((char*)d_ws + 4096 + whalf);
  const size_t listoff = 4096 + 2 * whalf;
  int* list = (int*)((char*)d_ws + listoff);
  int cap = 0;
  if (ws_size > listoff + 65536)
    cap = (int)min((size_t)32768, (ws_size - listoff) / 4);

  zero512<<<dim3(1), dim3(128), 0, stream>>>((int*)d_ws);
  const int n8 = E * H / 8;
  wconvert<<<dim3((n8 + 255) / 256), 256, 0, stream>>>(w, Whi, Wlo, n8, H);
  gemm_fused<<<dim3((int)(N / 64)), 256, 0, stream>>>(
      x, Whi, Wlo, bias, S, wout, iout, cnt, hist, list, cap, H, K);
  recompute_f64<<<dim3(512), 256, 0, stream>>>(x, w, bias, S, wout, iout, cnt,
                                               list, hist, H, K, cap);
  bias_update<<<dim3(1), dim3(E), 0, stream>>>(hist, bias, bout,
                                               (float)((double)N * K / E));
}